// Round 1
// baseline (229.323 us; speedup 1.0000x reference)
//
#include <hip/hip_runtime.h>

// Problem constants (B=1)
constexpr int DD = 8, HH = 24, WW = 24;
constexpr int NQ = DD * HH * WW;      // 4608 query positions
constexpr int CIN = 192;
constexpr int CQKV = 576;             // 3 scales * 192
constexpr float ATT_SCALE = 0.17677669529663687f;  // 32^-0.5

// ---------------------------------------------------------------------------
// GEMM with bias: C[M,N] = A[M,K] @ B[K,N] + bias[N]
// BM=64, BN=64, BK=32, 256 threads, 4x4 micro-tile.
// M%64==0, N%64==0, K%32==0 (4608/576/192/192 all satisfy).
// ---------------------------------------------------------------------------
__global__ __launch_bounds__(256)
void gemm_bias_kernel(const float* __restrict__ A, const float* __restrict__ B,
                      const float* __restrict__ bias, float* __restrict__ C,
                      int M, int N, int K)
{
    constexpr int BM = 64, BN = 64, BK = 32;
    __shared__ float As[BM][BK + 4];   // +4 pad keeps float4 alignment, breaks conflicts
    __shared__ float Bs[BK][BN];

    const int tid = threadIdx.x;
    const int tx = tid & 15;           // 16 col-groups
    const int ty = tid >> 4;           // 16 row-groups
    const int tx4 = tx * 4, ty4 = ty * 4;
    const int bm = blockIdx.x * BM;
    const int bn = blockIdx.y * BN;

    float acc[4][4] = {};

    for (int kk = 0; kk < K; kk += BK) {
        // Load A tile: 64x32 = 512 float4, 2 per thread
        #pragma unroll
        for (int v = 0; v < BM * BK / 4; v += 256) {
            int idx = v + tid;
            int r = idx >> 3;              // 8 float4 per A row
            int c = (idx & 7) << 2;
            *(float4*)(&As[r][c]) = *(const float4*)(A + (long)(bm + r) * K + kk + c);
        }
        // Load B tile: 32x64 = 512 float4, 2 per thread
        #pragma unroll
        for (int v = 0; v < BK * BN / 4; v += 256) {
            int idx = v + tid;
            int r = idx >> 4;              // 16 float4 per B row
            int c = (idx & 15) << 2;
            *(float4*)(&Bs[r][c]) = *(const float4*)(B + (long)(kk + r) * N + bn + c);
        }
        __syncthreads();
        #pragma unroll
        for (int k2 = 0; k2 < BK; ++k2) {
            float a0 = As[ty4 + 0][k2];
            float a1 = As[ty4 + 1][k2];
            float a2 = As[ty4 + 2][k2];
            float a3 = As[ty4 + 3][k2];
            float4 b = *(const float4*)(&Bs[k2][tx4]);
            acc[0][0] += a0 * b.x; acc[0][1] += a0 * b.y; acc[0][2] += a0 * b.z; acc[0][3] += a0 * b.w;
            acc[1][0] += a1 * b.x; acc[1][1] += a1 * b.y; acc[1][2] += a1 * b.z; acc[1][3] += a1 * b.w;
            acc[2][0] += a2 * b.x; acc[2][1] += a2 * b.y; acc[2][2] += a2 * b.z; acc[2][3] += a2 * b.w;
            acc[3][0] += a3 * b.x; acc[3][1] += a3 * b.y; acc[3][2] += a3 * b.z; acc[3][3] += a3 * b.w;
        }
        __syncthreads();
    }

    const float4 bv = *(const float4*)(bias + bn + tx4);
    #pragma unroll
    for (int i = 0; i < 4; ++i) {
        float4 o;
        o.x = acc[i][0] + bv.x;
        o.y = acc[i][1] + bv.y;
        o.z = acc[i][2] + bv.z;
        o.w = acc[i][3] + bv.w;
        *(float4*)(C + (long)(bm + ty4 + i) * N + bn + tx4) = o;
    }
}

// ---------------------------------------------------------------------------
// Neighborhood attention, one wave per (query, scale).
// lane = h*32 + slot; h = head within scale, slot = neighbor-slot / out-dim.
// qkv row layout (576 ch): [scale][q/k/v][head][32]  (q at +0, k at +64, v at +128)
// LDS per wave: 2112 floats, reused as logits[2][K^3] then red[2][32][33].
// All LDS traffic is wave-local -> no __syncthreads needed.
// ---------------------------------------------------------------------------
template<int K>
__device__ __forceinline__
void attn_wave(const float* __restrict__ qkv, float* __restrict__ y,
               int q, int scale, int lane, float* __restrict__ lds)
{
    constexpr int K3 = K * K * K;
    const int h = lane >> 5;
    const int slot = lane & 31;

    const int wq = q % WW;
    const int hq = (q / WW) % HH;
    const int dq = q / (WW * HH);

    int sd = dq - K / 2; sd = sd < 0 ? 0 : (sd > DD - K ? DD - K : sd);
    int sh = hq - K / 2; sh = sh < 0 ? 0 : (sh > HH - K ? HH - K : sh);
    int sw = wq - K / 2; sw = sw < 0 ? 0 : (sw > WW - K ? WW - K : sw);

    const float* base = qkv + (long)((sd * HH + sh) * WW + sw) * CQKV + scale * 192 + h * 32;

    // q fragment into registers (broadcast load: all 32 lanes of the head group
    // hit the same addresses -> single fetch)
    const float4* qp = reinterpret_cast<const float4*>(qkv + (long)q * CQKV + scale * 192 + h * 32);
    float4 qv[8];
    #pragma unroll
    for (int t = 0; t < 8; ++t) qv[t] = qp[t];

    // ---- pass 1: logits ----
    for (int n = slot; n < K3; n += 32) {
        int i = n / (K * K);
        int rem = n - i * (K * K);
        int j = rem / K;
        int l = rem - j * K;
        int off = (i * (HH * WW) + j * WW + l) * CQKV;
        const float4* kp = reinterpret_cast<const float4*>(base + 64 + off);
        float dot = 0.f;
        #pragma unroll
        for (int t = 0; t < 8; ++t) {
            float4 kkv = kp[t];
            dot += qv[t].x * kkv.x + qv[t].y * kkv.y + qv[t].z * kkv.z + qv[t].w * kkv.w;
        }
        lds[h * K3 + n] = dot * ATT_SCALE;
    }
    asm volatile("s_waitcnt lgkmcnt(0)" ::: "memory");

    // ---- softmax (within 32-lane head group) ----
    float m = -1e30f;
    for (int n = slot; n < K3; n += 32) m = fmaxf(m, lds[h * K3 + n]);
    #pragma unroll
    for (int o = 16; o >= 1; o >>= 1) m = fmaxf(m, __shfl_xor(m, o));

    float lsum = 0.f;
    for (int n = slot; n < K3; n += 32) {
        float p = __expf(lds[h * K3 + n] - m);
        lds[h * K3 + n] = p;
        lsum += p;
    }
    #pragma unroll
    for (int o = 16; o >= 1; o >>= 1) lsum += __shfl_xor(lsum, o);
    const float rl = 1.0f / lsum;
    asm volatile("s_waitcnt lgkmcnt(0)" ::: "memory");

    // ---- PV: each lane accumulates a partial 32-dim output over its neighbors ----
    float4 acc[8];
    #pragma unroll
    for (int t = 0; t < 8; ++t) acc[t] = make_float4(0.f, 0.f, 0.f, 0.f);

    for (int n = slot; n < K3; n += 32) {
        int i = n / (K * K);
        int rem = n - i * (K * K);
        int j = rem / K;
        int l = rem - j * K;
        int off = (i * (HH * WW) + j * WW + l) * CQKV;
        float p = lds[h * K3 + n];   // own write, wave-local
        const float4* vp = reinterpret_cast<const float4*>(base + 128 + off);
        #pragma unroll
        for (int t = 0; t < 8; ++t) {
            float4 vv = vp[t];
            acc[t].x += p * vv.x;
            acc[t].y += p * vv.y;
            acc[t].z += p * vv.z;
            acc[t].w += p * vv.w;
        }
    }

    // ---- cross-lane reduce via LDS transpose: red[h][d][slot], stride 33 ----
    #pragma unroll
    for (int t = 0; t < 8; ++t) {
        lds[h * 1056 + (4 * t + 0) * 33 + slot] = acc[t].x;
        lds[h * 1056 + (4 * t + 1) * 33 + slot] = acc[t].y;
        lds[h * 1056 + (4 * t + 2) * 33 + slot] = acc[t].z;
        lds[h * 1056 + (4 * t + 3) * 33 + slot] = acc[t].w;
    }
    asm volatile("s_waitcnt lgkmcnt(0)" ::: "memory");

    // lane role switch: d = slot
    float s0 = 0.f, s1 = 0.f, s2 = 0.f, s3 = 0.f;
    #pragma unroll
    for (int ss = 0; ss < 32; ss += 4) {
        s0 += lds[h * 1056 + slot * 33 + ss + 0];
        s1 += lds[h * 1056 + slot * 33 + ss + 1];
        s2 += lds[h * 1056 + slot * 33 + ss + 2];
        s3 += lds[h * 1056 + slot * 33 + ss + 3];
    }
    y[(long)q * CIN + scale * 64 + lane] = (s0 + s1 + s2 + s3) * rl;
}

__global__ __launch_bounds__(256)
void na3d_attn_kernel(const float* __restrict__ qkv, float* __restrict__ y)
{
    __shared__ float lds[4][2112];
    const int wave = threadIdx.x >> 6;
    const int lane = threadIdx.x & 63;
    const int task = blockIdx.x * 4 + wave;     // 13824 tasks, scale-major
    const int scale = task / NQ;                // blocks are scale-uniform (NQ%4==0)
    const int q = task - scale * NQ;
    float* wlds = lds[wave];

    if (scale == 0)      attn_wave<3>(qkv, y, q, 0, lane, wlds);
    else if (scale == 1) attn_wave<5>(qkv, y, q, 1, lane, wlds);
    else                 attn_wave<7>(qkv, y, q, 2, lane, wlds);
}

// ---------------------------------------------------------------------------
extern "C" void kernel_launch(void* const* d_in, const int* in_sizes, int n_in,
                              void* d_out, int out_size, void* d_ws, size_t ws_size,
                              hipStream_t stream)
{
    const float* x      = (const float*)d_in[0];   // [4608,192]
    const float* W_qkv  = (const float*)d_in[1];   // [192,576]
    const float* b_qkv  = (const float*)d_in[2];   // [576]
    const float* W_proj = (const float*)d_in[3];   // [192,192]
    const float* b_proj = (const float*)d_in[4];   // [192]
    float* out = (float*)d_out;                    // [4608,192]

    float* qkv = (float*)d_ws;                     // 4608*576 floats = 10.6 MB
    float* y   = qkv + (long)NQ * CQKV;            // 4608*192 floats = 3.5 MB

    // 1) qkv = x @ W_qkv + b_qkv
    gemm_bias_kernel<<<dim3(NQ / 64, CQKV / 64), 256, 0, stream>>>(x, W_qkv, b_qkv, qkv, NQ, CQKV, CIN);
    // 2) multi-scale neighborhood attention -> y
    na3d_attn_kernel<<<dim3(3 * NQ / 4), 256, 0, stream>>>(qkv, y);
    // 3) out = y @ W_proj + b_proj
    gemm_bias_kernel<<<dim3(NQ / 64, CIN / 64), 256, 0, stream>>>(y, W_proj, b_proj, out, NQ, CIN, CIN);
}

// Round 2
// 166.220 us; speedup vs baseline: 1.3796x; 1.3796x over previous
//
#include <hip/hip_runtime.h>

// Problem constants (B=1)
constexpr int DD = 8, HH = 24, WW = 24;
constexpr int NQ = DD * HH * WW;      // 4608 query positions
constexpr int CIN = 192;
constexpr int CQKV = 576;             // 3 scales * 192
constexpr float ATT_SCALE = 0.17677669529663687f;  // 32^-0.5

// ---------------------------------------------------------------------------
// GEMM with bias: C[M,N] = A[M,K] @ B[K,N] + bias[N]
// BM=64, BN=64, BK=32, 256 threads, 4x4 micro-tile.
// As stored TRANSPOSED [BK][BM+1] so inner loop reads one b128 per operand.
// ---------------------------------------------------------------------------
__global__ __launch_bounds__(256)
void gemm_bias_kernel(const float* __restrict__ A, const float* __restrict__ B,
                      const float* __restrict__ bias, float* __restrict__ C,
                      int M, int N, int K)
{
    constexpr int BM = 64, BN = 64, BK = 32;
    __shared__ float As[BK][BM + 1];   // transposed; +1 breaks store conflicts
    __shared__ float Bs[BK][BN];

    const int tid = threadIdx.x;
    const int tx = tid & 15;           // 16 col-groups
    const int ty = tid >> 4;           // 16 row-groups
    const int tx4 = tx * 4, ty4 = ty * 4;
    const int bm = blockIdx.x * BM;
    const int bn = blockIdx.y * BN;

    float acc[4][4] = {};

    for (int kk = 0; kk < K; kk += BK) {
        // Load A tile 64x32 (512 float4, 2/thread), store transposed
        #pragma unroll
        for (int v = 0; v < BM * BK / 4; v += 256) {
            int idx = v + tid;
            int r = idx >> 3;              // 8 float4 per A row
            int c = (idx & 7) << 2;
            float4 a = *(const float4*)(A + (long)(bm + r) * K + kk + c);
            As[c + 0][r] = a.x;
            As[c + 1][r] = a.y;
            As[c + 2][r] = a.z;
            As[c + 3][r] = a.w;
        }
        // Load B tile 32x64 (512 float4, 2/thread)
        #pragma unroll
        for (int v = 0; v < BK * BN / 4; v += 256) {
            int idx = v + tid;
            int r = idx >> 4;              // 16 float4 per B row
            int c = (idx & 15) << 2;
            *(float4*)(&Bs[r][c]) = *(const float4*)(B + (long)(kk + r) * N + bn + c);
        }
        __syncthreads();
        #pragma unroll
        for (int k2 = 0; k2 < BK; ++k2) {
            float4 a = *(const float4*)(&As[k2][ty4]);
            float4 b = *(const float4*)(&Bs[k2][tx4]);
            acc[0][0] += a.x * b.x; acc[0][1] += a.x * b.y; acc[0][2] += a.x * b.z; acc[0][3] += a.x * b.w;
            acc[1][0] += a.y * b.x; acc[1][1] += a.y * b.y; acc[1][2] += a.y * b.z; acc[1][3] += a.y * b.w;
            acc[2][0] += a.z * b.x; acc[2][1] += a.z * b.y; acc[2][2] += a.z * b.z; acc[2][3] += a.z * b.w;
            acc[3][0] += a.w * b.x; acc[3][1] += a.w * b.y; acc[3][2] += a.w * b.z; acc[3][3] += a.w * b.w;
        }
        __syncthreads();
    }

    const float4 bv = *(const float4*)(bias + bn + tx4);
    #pragma unroll
    for (int i = 0; i < 4; ++i) {
        float4 o;
        o.x = acc[i][0] + bv.x;
        o.y = acc[i][1] + bv.y;
        o.z = acc[i][2] + bv.z;
        o.w = acc[i][3] + bv.w;
        *(float4*)(C + (long)(bm + ty4 + i) * N + bn + tx4) = o;
    }
}

// ---------------------------------------------------------------------------
// Flash-style neighborhood attention.
// One block per (scale, d, h) query row: 24 queries x 2 heads.
// Thread t (384/block): w = t>>4 (24), hd = (t>>3)&1, d4 = t&7 (dim quad).
// Loop over K^2 neighbor (d,h) rows; each iteration stages the full 24-wide
// k/v row into double-buffered LDS (coalesced float4), then all queries
// consume their K-wide w-window with online softmax.
// 32-dim dot = 4-dim per-lane partial + shfl_xor(1,2,4) over the 8 d4-lanes.
// ---------------------------------------------------------------------------
constexpr int ROWF = 68;              // 64 ch + 4 pad (keeps 16B align, staggers banks)
constexpr int ROWBUF = WW * ROWF;     // 1632 floats per buffer

template<int K>
__device__ __forceinline__
void flash_row(const float* __restrict__ qkv, float* __restrict__ y,
               int dq, int hq, int scale,
               int w, int hd, int d4, int tid,
               float* __restrict__ ksh, float* __restrict__ vsh)
{
    constexpr int KK2 = K * K;

    int sd = dq - K / 2; sd = sd < 0 ? 0 : (sd > DD - K ? DD - K : sd);
    int sh = hq - K / 2; sh = sh < 0 ? 0 : (sh > HH - K ? HH - K : sh);
    int sw = w  - K / 2; sw = sw < 0 ? 0 : (sw > WW - K ? WW - K : sw);

    const int q = (dq * HH + hq) * WW + w;

    // q fragment (4 dims) in registers, pre-scaled
    float4 qv = *(const float4*)(qkv + (long)q * CQKV + scale * 192 + hd * 32 + d4 * 4);
    qv.x *= ATT_SCALE; qv.y *= ATT_SCALE; qv.z *= ATT_SCALE; qv.w *= ATT_SCALE;

    // cooperative-load indices (1 float4 of k and of v per thread)
    const int lwn = tid >> 4;          // 0..23
    const int lc  = (tid & 15) << 2;   // 0..60

    auto load_kv = [&](int buf, int ij) {
        int i = ij / K, j = ij - (ij / K) * K;
        const float* p = qkv + (long)(((sd + i) * HH + (sh + j)) * WW + lwn) * CQKV
                       + scale * 192 + lc;
        float4 kk = *(const float4*)(p + 64);
        float4 vv = *(const float4*)(p + 128);
        *(float4*)(ksh + buf * ROWBUF + lwn * ROWF + lc) = kk;
        *(float4*)(vsh + buf * ROWBUF + lwn * ROWF + lc) = vv;
    };

    float m = -1e30f, sum = 0.f;
    float4 acc = make_float4(0.f, 0.f, 0.f, 0.f);
    const int choff = hd * 32 + d4 * 4;

    load_kv(0, 0);
    int buf = 0;

    for (int ij = 0; ij < KK2; ++ij) {
        __syncthreads();
        if (ij + 1 < KK2) load_kv(buf ^ 1, ij + 1);

        const float* kb = ksh + buf * ROWBUF + choff;
        float lg[K];
        #pragma unroll
        for (int n = 0; n < K; ++n) {
            float4 kk = *(const float4*)(kb + (sw + n) * ROWF);
            float p = qv.x * kk.x + qv.y * kk.y + qv.z * kk.z + qv.w * kk.w;
            p += __shfl_xor(p, 1);
            p += __shfl_xor(p, 2);
            p += __shfl_xor(p, 4);
            lg[n] = p;
        }
        float mloc = lg[0];
        #pragma unroll
        for (int n = 1; n < K; ++n) mloc = fmaxf(mloc, lg[n]);
        float mnew = fmaxf(m, mloc);
        float alpha = __expf(m - mnew);
        m = mnew;
        sum *= alpha;
        acc.x *= alpha; acc.y *= alpha; acc.z *= alpha; acc.w *= alpha;

        const float* vb = vsh + buf * ROWBUF + choff;
        #pragma unroll
        for (int n = 0; n < K; ++n) {
            float pr = __expf(lg[n] - mnew);
            sum += pr;
            float4 vv = *(const float4*)(vb + (sw + n) * ROWF);
            acc.x += pr * vv.x;
            acc.y += pr * vv.y;
            acc.z += pr * vv.z;
            acc.w += pr * vv.w;
        }
        buf ^= 1;
    }

    const float rs = 1.0f / sum;
    float4 o;
    o.x = acc.x * rs; o.y = acc.y * rs; o.z = acc.z * rs; o.w = acc.w * rs;
    *(float4*)(y + (long)q * CIN + scale * 64 + choff) = o;
}

__global__ __launch_bounds__(384)
void na3d_flash_kernel(const float* __restrict__ qkv, float* __restrict__ y)
{
    __shared__ float ksh[2 * ROWBUF];
    __shared__ float vsh[2 * ROWBUF];

    const int bid = blockIdx.x;          // 576 = 3 scales * 192 rows
    const int scale = bid % 3;           // interleave scales across CUs
    const int row = bid / 3;
    const int dq = row / HH, hq = row % HH;

    const int tid = threadIdx.x;
    const int w  = tid >> 4;
    const int hd = (tid >> 3) & 1;
    const int d4 = tid & 7;

    if (scale == 0)      flash_row<3>(qkv, y, dq, hq, 0, w, hd, d4, tid, ksh, vsh);
    else if (scale == 1) flash_row<5>(qkv, y, dq, hq, 1, w, hd, d4, tid, ksh, vsh);
    else                 flash_row<7>(qkv, y, dq, hq, 2, w, hd, d4, tid, ksh, vsh);
}

// ---------------------------------------------------------------------------
extern "C" void kernel_launch(void* const* d_in, const int* in_sizes, int n_in,
                              void* d_out, int out_size, void* d_ws, size_t ws_size,
                              hipStream_t stream)
{
    const float* x      = (const float*)d_in[0];   // [4608,192]
    const float* W_qkv  = (const float*)d_in[1];   // [192,576]
    const float* b_qkv  = (const float*)d_in[2];   // [576]
    const float* W_proj = (const float*)d_in[3];   // [192,192]
    const float* b_proj = (const float*)d_in[4];   // [192]
    float* out = (float*)d_out;                    // [4608,192]

    float* qkv = (float*)d_ws;                     // 4608*576 floats
    float* y   = qkv + (long)NQ * CQKV;            // 4608*192 floats

    // 1) qkv = x @ W_qkv + b_qkv
    gemm_bias_kernel<<<dim3(NQ / 64, CQKV / 64), 256, 0, stream>>>(x, W_qkv, b_qkv, qkv, NQ, CQKV, CIN);
    // 2) multi-scale neighborhood attention -> y
    na3d_flash_kernel<<<dim3(3 * DD * HH), 384, 0, stream>>>(qkv, y);
    // 3) out = y @ W_proj + b_proj
    gemm_bias_kernel<<<dim3(NQ / 64, CIN / 64), 256, 0, stream>>>(y, W_proj, b_proj, out, NQ, CIN, CIN);
}